// Round 1
// baseline (693.489 us; speedup 1.0000x reference)
//
#include <hip/hip_runtime.h>
#include <stdint.h>

#define HB 8
#define HL 128
#define HV 50257
#define HE 768
#define HM 400
#define HMT 800
#define HBL (HB*HL)

typedef __attribute__((ext_vector_type(4))) float f32x4;
typedef __attribute__((ext_vector_type(8))) short bf16x8;
typedef unsigned short u16;

struct u16x4 { u16 x, y, z, w; };

__device__ __forceinline__ u16 f2bf(float x){
  union { float f; uint32_t u; } v; v.f = x;
  uint32_t r = v.u + 0x7fffu + ((v.u >> 16) & 1u);
  return (u16)(r >> 16);
}

// ---- conversions -----------------------------------------------------------
__global__ __launch_bounds__(256) void cvt4_k(const float* __restrict__ src,
                                              u16* __restrict__ dst, long n4){
  long i = (long)blockIdx.x * 256 + threadIdx.x;
  long stride = (long)gridDim.x * 256;
  for (; i < n4; i += stride) {
    const float4 x = ((const float4*)src)[i];
    u16x4 y; y.x = f2bf(x.x); y.y = f2bf(x.y); y.z = f2bf(x.z); y.w = f2bf(x.w);
    ((u16x4*)dst)[i] = y;
  }
}

// W_node_cat[e][0:768]=W_s1[e], [768:1536]=W_n1[e]
__global__ __launch_bounds__(256) void build_wcat_k(const float* __restrict__ Ws1,
    const float* __restrict__ Wn1, u16* __restrict__ cat){
  int i = blockIdx.x * 256 + threadIdx.x;
  if (i >= HE*HE) return;
  int e = i / HE, k = i - e*HE;
  cat[(long)e*(2*HE) + k]      = f2bf(Ws1[i]);
  cat[(long)e*(2*HE) + HE + k] = f2bf(Wn1[i]);
}

// ---- GCN scatter: upd[t]+=cr[h]-rr; upd[h]+=cr[t]-rr; cnt[t]++,cnt[h]++ ----
__global__ __launch_bounds__(256) void scatter_k(const float* __restrict__ wte,
    const float* __restrict__ rel, const int* __restrict__ cids,
    const int* __restrict__ rids, const int* __restrict__ head,
    const int* __restrict__ tail, float* __restrict__ upd, float* __restrict__ cnt){
  int idx = blockIdx.x;               // 0..B*MT-1
  int b = idx / HMT, j = idx - b*HMT;
  int h = head[b*HMT+j], t = tail[b*HMT+j];
  const float* rr = rel + (long)rids[b*HMT+j]*HE;
  const float* ch = wte + (long)cids[b*HM+h]*HE;
  const float* ct = wte + (long)cids[b*HM+t]*HE;
  float* ut = upd + ((long)b*HM + t)*HE;
  float* uh = upd + ((long)b*HM + h)*HE;
  for (int e = threadIdx.x; e < HE; e += 256) {
    float rv = rr[e];
    atomicAdd(&ut[e], ch[e] - rv);
    atomicAdd(&uh[e], ct[e] - rv);
  }
  if (threadIdx.x == 0) {
    atomicAdd(&cnt[b*HM+t], 1.f);
    atomicAdd(&cnt[b*HM+h], 1.f);
  }
}

// A_node[row][0:768]=bf16(cr), [768:1536]=bf16(upd/clip(cnt,1))
__global__ __launch_bounds__(256) void build_anode_k(const float* __restrict__ wte,
    const int* __restrict__ cids, const float* __restrict__ upd,
    const float* __restrict__ cnt, u16* __restrict__ An){
  int row = blockIdx.x;               // 0..B*M-1
  int b = row / HM, m = row - b*HM;
  const float* crow = wte + (long)cids[b*HM+m]*HE;
  float ic = 1.f / fmaxf(cnt[row], 1.f);
  for (int e = threadIdx.x; e < HE; e += 256) {
    An[(long)row*(2*HE) + e]      = f2bf(crow[e]);
    An[(long)row*(2*HE) + HE + e] = f2bf(upd[(long)row*HE + e] * ic);
  }
}

__global__ __launch_bounds__(256) void build_rrep_k(const float* __restrict__ rel,
    const int* __restrict__ rids, u16* __restrict__ rrep){
  int row = blockIdx.x;               // 0..B*MT-1
  int b = row / HMT, j = row - b*HMT;
  const float* rr = rel + (long)rids[b*HMT+j]*HE;
  for (int e = threadIdx.x; e < HE; e += 256)
    rrep[(long)row*HE + e] = f2bf(rr[e]);
}

// triple_repr[row][0:768]=node[head], [1536:2304]=node[tail] (raw bf16 copy)
__global__ __launch_bounds__(256) void gather_ht_k(const u16* __restrict__ node,
    const int* __restrict__ head, const int* __restrict__ tail, u16* __restrict__ trep){
  int row = blockIdx.x;               // 0..B*MT-1
  int b = row / HMT, j = row - b*HMT;
  const u16* nh = node + ((long)b*HM + head[b*HMT+j])*HE;
  const u16* nt = node + ((long)b*HM + tail[b*HMT+j])*HE;
  u16* dst = trep + (long)row*(3*HE);
  for (int e = threadIdx.x; e < HE; e += 256) {
    dst[e]        = nh[e];
    dst[2*HE + e] = nt[e];
  }
}

// ---- generic MFMA GEMM: C[M,N] = act(A[M,K] @ B[N,K]^T) ---------------------
// 128x128 tile, BK=32, 4 waves 2x2, 16x16x32 bf16 MFMA, global_load_lds staging.
// M must be a multiple of 128; N is bounds-checked (B rows clamped on load).
template<int ACT, int OUTBF16>
__global__ __launch_bounds__(256) void gemm_bt(
    const u16* __restrict__ A, const u16* __restrict__ Bm, void* __restrict__ Cout,
    int Mdim, int Ndim, int Kdim, int ldc, long Abs, long Bbs, long Cbs)
{
  __shared__ alignas(16) u16 Asm[128*32];
  __shared__ alignas(16) u16 Bsm[128*32];
  const int bz = blockIdx.z;
  const u16* Ab = A + (long)bz * Abs;
  const u16* Bb = Bm + (long)bz * Bbs;
  const int m0 = blockIdx.y * 128;
  const int n0 = blockIdx.x * 128;
  const int tid = threadIdx.x;
  const int lane = tid & 63;
  const int wid = tid >> 6;
  const int wr = wid >> 1, wc = wid & 1;

  f32x4 acc[4][4] = {};

  for (int k0 = 0; k0 < Kdim; k0 += 32) {
    #pragma unroll
    for (int i = 0; i < 2; ++i) {
      const int c = wid*128 + i*64 + lane;   // chunk 0..511
      const int row = c >> 2, seg = c & 3;   // [128][4x16B] row-major
      const u16* ga = Ab + (long)(m0 + row) * Kdim + k0 + seg*8;
      __builtin_amdgcn_global_load_lds(
          (const __attribute__((address_space(1))) void*)ga,
          (__attribute__((address_space(3))) void*)&Asm[(wid*128 + i*64)*8], 16, 0, 0);
      int rn = n0 + row; if (rn > Ndim-1) rn = Ndim-1;
      const u16* gb = Bb + (long)rn * Kdim + k0 + seg*8;
      __builtin_amdgcn_global_load_lds(
          (const __attribute__((address_space(1))) void*)gb,
          (__attribute__((address_space(3))) void*)&Bsm[(wid*128 + i*64)*8], 16, 0, 0);
    }
    __syncthreads();
    const int frow = lane & 15;
    const int koff = (lane >> 4) * 8;
    bf16x8 af[4], bfr[4];
    #pragma unroll
    for (int mi = 0; mi < 4; ++mi)
      af[mi] = *(const bf16x8*)&Asm[(wr*64 + mi*16 + frow)*32 + koff];
    #pragma unroll
    for (int ni = 0; ni < 4; ++ni)
      bfr[ni] = *(const bf16x8*)&Bsm[(wc*64 + ni*16 + frow)*32 + koff];
    #pragma unroll
    for (int mi = 0; mi < 4; ++mi)
      #pragma unroll
      for (int ni = 0; ni < 4; ++ni)
        acc[mi][ni] = __builtin_amdgcn_mfma_f32_16x16x32_bf16(af[mi], bfr[ni], acc[mi][ni], 0, 0, 0);
    __syncthreads();
  }

  const long cb = (long)bz * Cbs;
  const int cr0 = m0 + wr*64 + ((lane >> 4) * 4);
  const int cc0 = n0 + wc*64 + (lane & 15);
  #pragma unroll
  for (int mi = 0; mi < 4; ++mi) {
    #pragma unroll
    for (int ni = 0; ni < 4; ++ni) {
      const int col = cc0 + ni*16;
      if (col < Ndim) {
        #pragma unroll
        for (int r = 0; r < 4; ++r) {
          const int rowi = cr0 + mi*16 + r;
          float v = acc[mi][ni][r];
          if (ACT == 1) v = fmaxf(v, 0.f);
          if (ACT == 2) v = 1.f / (1.f + __expf(-v));
          if (OUTBF16) ((u16*)Cout)[cb + (long)rowi*ldc + col] = f2bf(v);
          else        ((float*)Cout)[cb + (long)rowi*ldc + col] = v;
        }
      }
    }
  }
}

// ---- per-row online softmax stats over V -----------------------------------
__global__ __launch_bounds__(256) void rowstat_k(const float* __restrict__ logits,
    float* __restrict__ rmax, float* __restrict__ rsum){
  int r = blockIdx.x;
  const float* row = logits + (long)r * HV;
  float mx = -3.4e38f, sm = 0.f;
  for (int v = threadIdx.x; v < HV; v += 256) {
    float x = row[v];
    if (x <= mx) sm += __expf(x - mx);
    else { sm = sm * __expf(mx - x) + 1.f; mx = x; }
  }
  __shared__ float smx[256], ssm[256];
  smx[threadIdx.x] = mx; ssm[threadIdx.x] = sm;
  __syncthreads();
  for (int s = 128; s > 0; s >>= 1) {
    if ((int)threadIdx.x < s) {
      float m1 = smx[threadIdx.x], s1 = ssm[threadIdx.x];
      float m2 = smx[threadIdx.x+s], s2 = ssm[threadIdx.x+s];
      float Mv = fmaxf(m1, m2);
      smx[threadIdx.x] = Mv;
      ssm[threadIdx.x] = s1*__expf(m1-Mv) + s2*__expf(m2-Mv);
    }
    __syncthreads();
  }
  if (threadIdx.x == 0) { rmax[r] = smx[0]; rsum[r] = ssm[0]; }
}

// ---- gate = sigmoid(h . gate_w + gate_b), one wave per row ------------------
__global__ __launch_bounds__(256) void gate_k(const float* __restrict__ hs,
    const float* __restrict__ gw, const float* __restrict__ gb, float* __restrict__ gate){
  int row = blockIdx.x*4 + (threadIdx.x >> 6);
  int lane = threadIdx.x & 63;
  const float* h = hs + (long)row * HE;
  float s = 0.f;
  for (int e = lane; e < HE; e += 64) s += h[e] * gw[e];
  for (int o = 32; o; o >>= 1) s += __shfl_down(s, o);
  if (lane == 0) gate[row] = 1.f / (1.f + __expf(-(s + gb[0])));
}

// ---- multi-hop scatter/gather + softmax over M, per (b,l) -------------------
__global__ __launch_bounds__(256) void multihop_k(const float* __restrict__ tprob,
    const int* __restrict__ head, const int* __restrict__ tail,
    const int* __restrict__ labels, const int* __restrict__ dist,
    float* __restrict__ cprob){
  const int bl = blockIdx.x;          // 0..1023
  const int b = bl >> 7;
  const int tid = threadIdx.x;
  const int lane = tid & 63, wid = tid >> 6;
  __shared__ float ns[HM], sacc[HM], tot[HM], invc[HM], dec[HM];
  __shared__ float red[16];
  const int* hb = head + b*HMT;
  const int* tb = tail + b*HMT;
  const int* lb = labels + b*HMT;
  const float* tpl = tprob + (long)bl * HMT;

  for (int m = tid; m < HM; m += 256) {
    int d = dist[b*HM + m];
    float im = (d == 0) ? 1.f : 0.f;
    ns[m] = im; tot[m] = im * -100000.f;
    dec[m] = (d == 0) ? 1.f : ((d == 1) ? 0.8f : 0.64f);
    sacc[m] = 0.f; invc[m] = 0.f;
  }
  __syncthreads();
  for (int j = tid; j < HMT; j += 256) atomicAdd(&invc[tb[j]], 1.f);
  __syncthreads();
  for (int m = tid; m < HM; m += 256) invc[m] = 1.f / fmaxf(invc[m], 1.f);
  __syncthreads();

  for (int hop = 0; hop < 2; ++hop) {
    for (int j = tid; j < HMT; j += 256) {
      float tpv = (lb[j] == -1) ? 0.f : tpl[j];
      float u = ns[hb[j]] * 0.8f + tpv;
      atomicAdd(&sacc[tb[j]], u);
    }
    __syncthreads();
    for (int m = tid; m < HM; m += 256) {
      float v = sacc[m] * invc[m];
      ns[m] = v; tot[m] += v * dec[m]; sacc[m] = 0.f;
    }
    __syncthreads();
  }

  // softmax over tot[0..399]
  float lmx = -3.4e38f;
  for (int m = tid; m < HM; m += 256) lmx = fmaxf(lmx, tot[m]);
  for (int o = 32; o; o >>= 1) lmx = fmaxf(lmx, __shfl_down(lmx, o));
  if (lane == 0) red[wid] = lmx;
  __syncthreads();
  float gmx = fmaxf(fmaxf(red[0], red[1]), fmaxf(red[2], red[3]));
  float ls = 0.f;
  for (int m = tid; m < HM; m += 256) ls += __expf(tot[m] - gmx);
  for (int o = 32; o; o >>= 1) ls += __shfl_down(ls, o);
  if (lane == 0) red[8 + wid] = ls;
  __syncthreads();
  float inv = 1.f / (red[8] + red[9] + red[10] + red[11]);
  float* outrow = cprob + (long)bl * HM;
  for (int m = tid; m < HM; m += 256) outrow[m] = __expf(tot[m] - gmx) * inv;
}

// ---- final blend, in-place over d_out (logits -> probs) --------------------
__global__ __launch_bounds__(256) void finalize_k(float* __restrict__ out,
    const float* __restrict__ rmax, const float* __restrict__ rsum,
    const float* __restrict__ gate, const float* __restrict__ cprob,
    const int* __restrict__ vmap, const int* __restrict__ mmask){
  const long base = ((long)blockIdx.x * 256 + threadIdx.x) * 4;
  float4 x = *(float4*)&out[base];
  float r4[4];
  const float* xs = (const float*)&x;
  #pragma unroll
  for (int i = 0; i < 4; ++i) {
    unsigned idx = (unsigned)base + i;
    unsigned r = idx / 50257u;          // compiler magic-multiply
    unsigned v = idx - r * 50257u;
    float g = gate[r];
    float lm = __expf(xs[i] - rmax[r]) / rsum[r];
    float cp = (mmask[v] != 0) ? cprob[r*400u + vmap[v]] : 0.f;
    r4[i] = g * cp + (1.f - g) * lm;
  }
  float4 y; y.x = r4[0]; y.y = r4[1]; y.z = r4[2]; y.w = r4[3];
  *(float4*)&out[base] = y;
}

// ---------------------------------------------------------------------------
extern "C" void kernel_launch(void* const* d_in, const int* in_sizes, int n_in,
                              void* d_out, int out_size, void* d_ws, size_t ws_size,
                              hipStream_t stream)
{
  const float* hs   = (const float*)d_in[0];
  const float* wte  = (const float*)d_in[1];
  const float* rel  = (const float*)d_in[2];
  const float* Ws   = (const float*)d_in[3];
  const float* Wn   = (const float*)d_in[4];
  const float* Wr   = (const float*)d_in[5];
  const float* Wt   = (const float*)d_in[6];
  const float* gw   = (const float*)d_in[7];
  const float* gb   = (const float*)d_in[8];
  const int* cids   = (const int*)d_in[9];
  const int* rids   = (const int*)d_in[10];
  const int* head   = (const int*)d_in[11];
  const int* tail   = (const int*)d_in[12];
  const int* labels = (const int*)d_in[13];
  const int* dist   = (const int*)d_in[14];
  const int* vmap   = (const int*)d_in[15];
  const int* mmask  = (const int*)d_in[16];
  float* out = (float*)d_out;

  char* ws = (char*)d_ws;
  size_t o = 0;
  auto alloc = [&](size_t bytes) -> char* {
    char* p = ws + o; o = (o + bytes + 255) & ~(size_t)255; return p;
  };
  u16* wte_b = (u16*)alloc((size_t)HV*HE*2);        // 77.2 MB
  u16* hid_b = (u16*)alloc((size_t)HBL*HE*2);       // 1.6 MB
  u16* wcat  = (u16*)alloc((size_t)HE*2*HE*2);      // 2.4 MB
  u16* wr1   = (u16*)alloc((size_t)HE*HE*2);        // 1.2 MB
  u16* wt_b  = (u16*)alloc((size_t)HE*3*HE*2);      // 3.5 MB
  u16* anode = (u16*)alloc((size_t)HB*HM*2*HE*2);   // 9.8 MB
  u16* rrep  = (u16*)alloc((size_t)HB*HMT*HE*2);    // 9.8 MB
  u16* nodeb = (u16*)alloc((size_t)HB*HM*HE*2);     // 4.9 MB
  u16* trep  = (u16*)alloc((size_t)HB*HMT*3*HE*2);  // 29.5 MB
  u16* tlb   = (u16*)alloc((size_t)HB*HMT*HE*2);    // 9.8 MB
  float* upd = (float*)alloc((size_t)HB*HM*HE*4);   // 9.8 MB
  float* cnt = (float*)alloc((size_t)HB*HM*4);
  float* tprob = (float*)alloc((size_t)HB*HL*HMT*4);// 3.3 MB
  float* cprob = (float*)alloc((size_t)HB*HL*HM*4); // 1.6 MB
  float* rmax  = (float*)alloc(HBL*4);
  float* rsum  = (float*)alloc(HBL*4);
  float* gatev = (float*)alloc(HBL*4);
  (void)ws_size; (void)in_sizes; (void)n_in; (void)out_size;

  // conversions
  cvt4_k<<<4096, 256, 0, stream>>>(wte, wte_b, (long)HV*HE/4);
  cvt4_k<<<768, 256, 0, stream>>>(hs, hid_b, (long)HBL*HE/4);
  cvt4_k<<<576, 256, 0, stream>>>(Wr + (size_t)HE*HE, wr1, (long)HE*HE/4);
  cvt4_k<<<1728, 256, 0, stream>>>(Wt, wt_b, (long)HE*3*HE/4);
  build_wcat_k<<<(HE*HE+255)/256, 256, 0, stream>>>(Ws + (size_t)HE*HE, Wn + (size_t)HE*HE, wcat);

  // GCN (only hop 1 is live in the reference)
  hipMemsetAsync(upd, 0, (size_t)HB*HM*HE*4, stream);
  hipMemsetAsync(cnt, 0, (size_t)HB*HM*4, stream);
  scatter_k<<<HB*HMT, 256, 0, stream>>>(wte, rel, cids, rids, head, tail, upd, cnt);
  build_anode_k<<<HB*HM, 256, 0, stream>>>(wte, cids, upd, cnt, anode);
  build_rrep_k<<<HB*HMT, 256, 0, stream>>>(rel, rids, rrep);

  // node = relu(anode @ wcat^T)  (3200 x 768, K=1536)
  gemm_bt<1,1><<<dim3(6,25,1), 256, 0, stream>>>(anode, wcat, nodeb, 3200, 768, 1536, 768, 0, 0, 0);
  // relh -> triple_repr[:,768:1536]  (6400 x 768, K=768)
  gemm_bt<0,1><<<dim3(6,50,1), 256, 0, stream>>>(rrep, wr1, trep + HE, 6400, 768, 768, 3*HE, 0, 0, 0);
  gather_ht_k<<<HB*HMT, 256, 0, stream>>>(nodeb, head, tail, trep);
  // tl = triple_repr @ W_triple^T  (6400 x 768, K=2304)
  gemm_bt<0,1><<<dim3(6,50,1), 256, 0, stream>>>(trep, wt_b, tlb, 6400, 768, 2304, 768, 0, 0, 0);
  // triple_prob = sigmoid(hid @ tl^T) per batch  (128 x 800, K=768) x8
  gemm_bt<2,0><<<dim3(7,1,8), 256, 0, stream>>>(hid_b, tlb, tprob, 128, 800, 768, 800,
                                                (long)HL*HE, (long)HMT*HE, (long)HL*HMT);
  // logits = hid @ wte^T -> d_out  (1024 x 50257, K=768)
  gemm_bt<0,0><<<dim3(393,8,1), 256, 0, stream>>>(hid_b, wte_b, out, 1024, HV, 768, HV, 0, 0, 0);

  rowstat_k<<<HBL, 256, 0, stream>>>(out, rmax, rsum);
  gate_k<<<HBL/4, 256, 0, stream>>>(hs, gw, gb, gatev);
  multihop_k<<<HBL, 256, 0, stream>>>(tprob, head, tail, labels, dist, cprob);
  finalize_k<<<HV, 256, 0, stream>>>(out, rmax, rsum, gatev, cprob, vmap, mmask);
}

// Round 2
// 644.687 us; speedup vs baseline: 1.0757x; 1.0757x over previous
//
#include <hip/hip_runtime.h>
#include <stdint.h>

#define HB 8
#define HL 128
#define HV 50257
#define HE 768
#define HM 400
#define HMT 800
#define HBL (HB*HL)

typedef __attribute__((ext_vector_type(4))) float f32x4;
typedef __attribute__((ext_vector_type(8))) short bf16x8;
typedef unsigned short u16;

struct u16x4 { u16 x, y, z, w; };

__device__ __forceinline__ u16 f2bf(float x){
  union { float f; uint32_t u; } v; v.f = x;
  uint32_t r = v.u + 0x7fffu + ((v.u >> 16) & 1u);
  return (u16)(r >> 16);
}

// ---- conversions -----------------------------------------------------------
__global__ __launch_bounds__(256) void cvt4_k(const float* __restrict__ src,
                                              u16* __restrict__ dst, long n4){
  long i = (long)blockIdx.x * 256 + threadIdx.x;
  long stride = (long)gridDim.x * 256;
  for (; i < n4; i += stride) {
    const float4 x = ((const float4*)src)[i];
    u16x4 y; y.x = f2bf(x.x); y.y = f2bf(x.y); y.z = f2bf(x.z); y.w = f2bf(x.w);
    ((u16x4*)dst)[i] = y;
  }
}

// W_node_cat[e][0:768]=W_s1[e], [768:1536]=W_n1[e]
__global__ __launch_bounds__(256) void build_wcat_k(const float* __restrict__ Ws1,
    const float* __restrict__ Wn1, u16* __restrict__ cat){
  int i = blockIdx.x * 256 + threadIdx.x;
  if (i >= HE*HE) return;
  int e = i / HE, k = i - e*HE;
  cat[(long)e*(2*HE) + k]      = f2bf(Ws1[i]);
  cat[(long)e*(2*HE) + HE + k] = f2bf(Wn1[i]);
}

// ---- fused GCN scatter + anode build (per batch x 16-col chunk) ------------
// upd[t]+=cr[h]-rr; upd[h]+=cr[t]-rr; cnt via LDS atomics; emit bf16 A_node.
__global__ __launch_bounds__(256) void gcn_scatter_k(const float* __restrict__ wte,
    const float* __restrict__ rel, const int* __restrict__ cids,
    const int* __restrict__ rids, const int* __restrict__ head,
    const int* __restrict__ tail, u16* __restrict__ An){
  const int ch = blockIdx.x % 48;         // 48 chunks of 16 cols
  const int b  = blockIdx.x / 48;
  const int e0 = ch * 16;
  __shared__ float cw[HM][17];
  __shared__ float upd[HM][17];
  __shared__ float relc[40][17];
  __shared__ float cnt[HM];
  const int tid = threadIdx.x;

  for (int idx = tid; idx < HM*16; idx += 256) {
    int m = idx >> 4, e = idx & 15;
    cw[m][e] = wte[(long)cids[b*HM+m]*HE + e0 + e];
    upd[m][e] = 0.f;
  }
  for (int idx = tid; idx < 40*16; idx += 256) {
    int r = idx >> 4, e = idx & 15;
    relc[r][e] = rel[r*HE + e0 + e];
  }
  for (int m = tid; m < HM; m += 256) cnt[m] = 0.f;
  __syncthreads();

  for (int j = tid; j < HMT; j += 256) {
    int h = head[b*HMT+j], t = tail[b*HMT+j], r = rids[b*HMT+j];
    atomicAdd(&cnt[t], 1.f);
    atomicAdd(&cnt[h], 1.f);
    #pragma unroll
    for (int e = 0; e < 16; ++e) {
      float rv = relc[r][e];
      atomicAdd(&upd[t][e], cw[h][e] - rv);
      atomicAdd(&upd[h][e], cw[t][e] - rv);
    }
  }
  __syncthreads();

  for (int idx = tid; idx < HM*16; idx += 256) {
    int m = idx >> 4, e = idx & 15;
    float ic = 1.f / fmaxf(cnt[m], 1.f);
    u16* dst = An + ((long)b*HM + m) * (2*HE);
    dst[e0 + e]      = f2bf(cw[m][e]);
    dst[HE + e0 + e] = f2bf(upd[m][e] * ic);
  }
}

// ---- broadcast relW2 rows into P13[b][800..839] ----------------------------
__global__ __launch_bounds__(256) void bcast_relw2_k(const u16* __restrict__ relW2,
    u16* __restrict__ P13){
  int i = blockIdx.x*256 + threadIdx.x;     // 8*40*768
  if (i >= HB*40*HE) return;
  int b = i / (40*HE), rem = i - b*40*HE;
  P13[(long)b*840*HE + (long)800*HE + rem] = relW2[rem];
}

// ---- generic MFMA GEMM: C[M,N] = act(A[M,K] @ B[N,K]^T) ---------------------
// 128x128 tile, BK=32, 4 waves 2x2, 16x16x32 bf16 MFMA, global_load_lds staging.
// blockIdx.x = m-tile (fast, so consecutive blocks share the B n-tile),
// blockIdx.y = n-tile, blockIdx.z = batch. A and B rows clamped; C guarded.
template<int ACT, int OUTBF16, int ROWSUM>
__global__ __launch_bounds__(256) void gemm_bt(
    const u16* __restrict__ A, const u16* __restrict__ Bm, void* __restrict__ Cout,
    float* __restrict__ rowsum,
    int Mdim, int Ndim, int Kdim, int lda, int ldb, int ldc,
    long Abs, long Bbs, long Cbs)
{
  __shared__ alignas(16) u16 Asm[128*32];
  __shared__ alignas(16) u16 Bsm[128*32];
  const int bz = blockIdx.z;
  const u16* Ab = A + (long)bz * Abs;
  const u16* Bb = Bm + (long)bz * Bbs;
  const int m0 = blockIdx.x * 128;
  const int n0 = blockIdx.y * 128;
  const int tid = threadIdx.x;
  const int lane = tid & 63;
  const int wid = tid >> 6;
  const int wr = wid >> 1, wc = wid & 1;

  f32x4 acc[4][4] = {};

  for (int k0 = 0; k0 < Kdim; k0 += 32) {
    #pragma unroll
    for (int i = 0; i < 2; ++i) {
      const int c = wid*128 + i*64 + lane;   // chunk 0..511
      const int row = c >> 2, seg = c & 3;   // [128][4x16B] row-major
      int ra = m0 + row; if (ra > Mdim-1) ra = Mdim-1;
      const u16* ga = Ab + (long)ra * lda + k0 + seg*8;
      __builtin_amdgcn_global_load_lds(
          (const __attribute__((address_space(1))) void*)ga,
          (__attribute__((address_space(3))) void*)&Asm[(wid*128 + i*64)*8], 16, 0, 0);
      int rn = n0 + row; if (rn > Ndim-1) rn = Ndim-1;
      const u16* gb = Bb + (long)rn * ldb + k0 + seg*8;
      __builtin_amdgcn_global_load_lds(
          (const __attribute__((address_space(1))) void*)gb,
          (__attribute__((address_space(3))) void*)&Bsm[(wid*128 + i*64)*8], 16, 0, 0);
    }
    __syncthreads();
    const int frow = lane & 15;
    const int koff = (lane >> 4) * 8;
    bf16x8 af[4], bfr[4];
    #pragma unroll
    for (int mi = 0; mi < 4; ++mi)
      af[mi] = *(const bf16x8*)&Asm[(wr*64 + mi*16 + frow)*32 + koff];
    #pragma unroll
    for (int ni = 0; ni < 4; ++ni)
      bfr[ni] = *(const bf16x8*)&Bsm[(wc*64 + ni*16 + frow)*32 + koff];
    #pragma unroll
    for (int mi = 0; mi < 4; ++mi)
      #pragma unroll
      for (int ni = 0; ni < 4; ++ni)
        acc[mi][ni] = __builtin_amdgcn_mfma_f32_16x16x32_bf16(af[mi], bfr[ni], acc[mi][ni], 0, 0, 0);
    __syncthreads();
  }

  const long cb = (long)bz * Cbs;
  const int cr0 = m0 + wr*64 + ((lane >> 4) * 4);
  const int cc0 = n0 + wc*64 + (lane & 15);
  #pragma unroll
  for (int mi = 0; mi < 4; ++mi) {
    #pragma unroll
    for (int ni = 0; ni < 4; ++ni) {
      const int col = cc0 + ni*16;
      if (col < Ndim) {
        #pragma unroll
        for (int r = 0; r < 4; ++r) {
          const int rowi = cr0 + mi*16 + r;
          if (rowi < Mdim) {
            float v = acc[mi][ni][r];
            if (ACT == 1) v = fmaxf(v, 0.f);
            if (OUTBF16) ((u16*)Cout)[cb + (long)rowi*ldc + col] = f2bf(v);
            else        ((float*)Cout)[cb + (long)rowi*ldc + col] = v;
          }
        }
      }
    }
  }
  if (ROWSUM) {
    // per-row partial sum of exp(logit) over this block's 128 cols
    #pragma unroll
    for (int mi = 0; mi < 4; ++mi) {
      #pragma unroll
      for (int r = 0; r < 4; ++r) {
        float s = 0.f;
        #pragma unroll
        for (int ni = 0; ni < 4; ++ni) {
          const int col = cc0 + ni*16;
          s += (col < Ndim) ? __expf(acc[mi][ni][r]) : 0.f;
        }
        s += __shfl_xor(s, 8); s += __shfl_xor(s, 4);
        s += __shfl_xor(s, 2); s += __shfl_xor(s, 1);
        if ((lane & 15) == 0) {
          const int rowi = cr0 + mi*16 + r;
          if (rowi < Mdim) atomicAdd(&rowsum[rowi], s);
        }
      }
    }
  }
}

// ---- gate = sigmoid(h . gate_w + gate_b), one wave per row ------------------
__global__ __launch_bounds__(256) void gate_k(const float* __restrict__ hs,
    const float* __restrict__ gw, const float* __restrict__ gb, float* __restrict__ gate){
  int row = blockIdx.x*4 + (threadIdx.x >> 6);
  int lane = threadIdx.x & 63;
  const float* h = hs + (long)row * HE;
  float s = 0.f;
  for (int e = lane; e < HE; e += 64) s += h[e] * gw[e];
  for (int o = 32; o; o >>= 1) s += __shfl_down(s, o);
  if (lane == 0) gate[row] = 1.f / (1.f + __expf(-(s + gb[0])));
}

// ---- multi-hop: build triple_prob from factored scores, hops, softmax -------
// scores[b][l][840]: cols 0..399 = hs.P1 (head), 400..799 = hs.P3 (tail),
// 800..839 = hs.relW2 (relation).
__global__ __launch_bounds__(256) void multihop_k(const float* __restrict__ scores,
    const int* __restrict__ head, const int* __restrict__ tail,
    const int* __restrict__ rids, const int* __restrict__ labels,
    const int* __restrict__ dist, float* __restrict__ cprob){
  const int bl = blockIdx.x;          // 0..1023
  const int b = bl >> 7;
  const int tid = threadIdx.x;
  const int lane = tid & 63, wid = tid >> 6;
  __shared__ float srow[840];
  __shared__ float tp[HMT];
  __shared__ float ns[HM], sacc[HM], tot[HM], invc[HM], dec[HM];
  __shared__ float red[16];
  const int* hb = head + b*HMT;
  const int* tb = tail + b*HMT;
  const int* rb = rids + b*HMT;
  const int* lb = labels + b*HMT;
  const float* sr = scores + (long)bl * 840;

  for (int i = tid; i < 840; i += 256) srow[i] = sr[i];
  for (int m = tid; m < HM; m += 256) {
    int d = dist[b*HM + m];
    float im = (d == 0) ? 1.f : 0.f;
    ns[m] = im; tot[m] = im * -100000.f;
    dec[m] = (d == 0) ? 1.f : ((d == 1) ? 0.8f : 0.64f);
    sacc[m] = 0.f; invc[m] = 0.f;
  }
  __syncthreads();
  for (int j = tid; j < HMT; j += 256) {
    atomicAdd(&invc[tb[j]], 1.f);
    float x = srow[hb[j]] + srow[400 + tb[j]] + srow[800 + rb[j]];
    tp[j] = (lb[j] == -1) ? 0.f : 1.f / (1.f + __expf(-x));
  }
  __syncthreads();
  for (int m = tid; m < HM; m += 256) invc[m] = 1.f / fmaxf(invc[m], 1.f);
  __syncthreads();

  for (int hop = 0; hop < 2; ++hop) {
    for (int j = tid; j < HMT; j += 256) {
      float u = ns[hb[j]] * 0.8f + tp[j];
      atomicAdd(&sacc[tb[j]], u);
    }
    __syncthreads();
    for (int m = tid; m < HM; m += 256) {
      float v = sacc[m] * invc[m];
      ns[m] = v; tot[m] += v * dec[m]; sacc[m] = 0.f;
    }
    __syncthreads();
  }

  float lmx = -3.4e38f;
  for (int m = tid; m < HM; m += 256) lmx = fmaxf(lmx, tot[m]);
  for (int o = 32; o; o >>= 1) lmx = fmaxf(lmx, __shfl_down(lmx, o));
  if (lane == 0) red[wid] = lmx;
  __syncthreads();
  float gmx = fmaxf(fmaxf(red[0], red[1]), fmaxf(red[2], red[3]));
  float ls = 0.f;
  for (int m = tid; m < HM; m += 256) ls += __expf(tot[m] - gmx);
  for (int o = 32; o; o >>= 1) ls += __shfl_down(ls, o);
  if (lane == 0) red[8 + wid] = ls;
  __syncthreads();
  float inv = 1.f / (red[8] + red[9] + red[10] + red[11]);
  float* outrow = cprob + (long)bl * HM;
  for (int m = tid; m < HM; m += 256) outrow[m] = __expf(tot[m] - gmx) * inv;
}

// ---- final blend, in-place over d_out (logits -> probs) --------------------
__global__ __launch_bounds__(256) void finalize_k(float* __restrict__ out,
    const float* __restrict__ rsum, const float* __restrict__ gate,
    const float* __restrict__ cprob, const int* __restrict__ vmap,
    const int* __restrict__ mmask){
  const long base = ((long)blockIdx.x * 256 + threadIdx.x) * 4;
  float4 x = *(float4*)&out[base];
  float r4[4];
  const float* xs = (const float*)&x;
  #pragma unroll
  for (int i = 0; i < 4; ++i) {
    unsigned idx = (unsigned)base + i;
    unsigned r = idx / 50257u;
    unsigned v = idx - r * 50257u;
    float g = gate[r];
    float lm = __expf(xs[i]) / rsum[r];
    float cp = (mmask[v] != 0) ? cprob[r*400u + vmap[v]] : 0.f;
    r4[i] = g * cp + (1.f - g) * lm;
  }
  float4 y; y.x = r4[0]; y.y = r4[1]; y.z = r4[2]; y.w = r4[3];
  *(float4*)&out[base] = y;
}

// ---------------------------------------------------------------------------
extern "C" void kernel_launch(void* const* d_in, const int* in_sizes, int n_in,
                              void* d_out, int out_size, void* d_ws, size_t ws_size,
                              hipStream_t stream)
{
  const float* hs   = (const float*)d_in[0];
  const float* wte  = (const float*)d_in[1];
  const float* rel  = (const float*)d_in[2];
  const float* Ws   = (const float*)d_in[3];
  const float* Wn   = (const float*)d_in[4];
  const float* Wr   = (const float*)d_in[5];
  const float* Wt   = (const float*)d_in[6];
  const float* gw   = (const float*)d_in[7];
  const float* gb   = (const float*)d_in[8];
  const int* cids   = (const int*)d_in[9];
  const int* rids   = (const int*)d_in[10];
  const int* head   = (const int*)d_in[11];
  const int* tail   = (const int*)d_in[12];
  const int* labels = (const int*)d_in[13];
  const int* dist   = (const int*)d_in[14];
  const int* vmap   = (const int*)d_in[15];
  const int* mmask  = (const int*)d_in[16];
  float* out = (float*)d_out;

  char* ws = (char*)d_ws;
  size_t o = 0;
  auto alloc = [&](size_t bytes) -> char* {
    char* p = ws + o; o = (o + bytes + 255) & ~(size_t)255; return p;
  };
  u16* wte_b = (u16*)alloc((size_t)HV*HE*2);         // 77.2 MB
  u16* hid_b = (u16*)alloc((size_t)HBL*HE*2);        // 1.6 MB
  u16* wcat  = (u16*)alloc((size_t)HE*2*HE*2);       // 2.4 MB
  u16* wr1   = (u16*)alloc((size_t)HE*HE*2);         // 1.2 MB
  u16* wt_b  = (u16*)alloc((size_t)HE*3*HE*2);       // 3.5 MB
  u16* rel_b = (u16*)alloc((size_t)40*HE*2);
  u16* anode = (u16*)alloc((size_t)HB*HM*2*HE*2);    // 9.8 MB
  u16* nodeb = (u16*)alloc((size_t)HB*HM*HE*2);      // 4.9 MB
  u16* relWr = (u16*)alloc((size_t)40*HE*2);
  u16* relW2 = (u16*)alloc((size_t)40*HE*2);
  u16* P13   = (u16*)alloc((size_t)HB*840*HE*2);     // 10.3 MB
  float* scores = (float*)alloc((size_t)HB*HL*840*4);// 3.4 MB
  float* cprob  = (float*)alloc((size_t)HB*HL*HM*4); // 1.6 MB
  float* rowsum = (float*)alloc(HBL*4);
  float* gatev  = (float*)alloc(HBL*4);
  (void)ws_size; (void)in_sizes; (void)n_in; (void)out_size;

  // conversions
  cvt4_k<<<4096, 256, 0, stream>>>(wte, wte_b, (long)HV*HE/4);
  cvt4_k<<<768, 256, 0, stream>>>(hs, hid_b, (long)HBL*HE/4);
  cvt4_k<<<30, 256, 0, stream>>>(rel, rel_b, (long)40*HE/4);
  cvt4_k<<<576, 256, 0, stream>>>(Wr + (size_t)HE*HE, wr1, (long)HE*HE/4);
  cvt4_k<<<1728, 256, 0, stream>>>(Wt, wt_b, (long)HE*3*HE/4);
  build_wcat_k<<<(HE*HE+255)/256, 256, 0, stream>>>(Ws + (size_t)HE*HE, Wn + (size_t)HE*HE, wcat);
  hipMemsetAsync(rowsum, 0, HBL*4, stream);

  // fused GCN scatter -> anode (bf16 [8][400][1536])
  gcn_scatter_k<<<HB*48, 256, 0, stream>>>(wte, rel, cids, rids, head, tail, anode);

  // node = relu(anode @ wcat^T): batched, M=400, N=768, K=1536
  gemm_bt<1,1,0><<<dim3(4,6,8), 256, 0, stream>>>(anode, wcat, nodeb, nullptr,
      HM, HE, 2*HE, 2*HE, 2*HE, HE, (long)HM*2*HE, 0, (long)HM*HE);
  // relWr = rel @ Wr1^T  (40x768, K=768)
  gemm_bt<0,1,0><<<dim3(1,6,1), 256, 0, stream>>>(rel_b, wr1, relWr, nullptr,
      40, HE, HE, HE, HE, HE, 0, 0, 0);
  // relW2 = relWr @ Wt2^T (Wt cols 768..1535, ldb=2304)
  gemm_bt<0,1,0><<<dim3(1,6,1), 256, 0, stream>>>(relWr, wt_b + HE, relW2, nullptr,
      40, HE, HE, HE, 3*HE, HE, 0, 0, 0);
  // P1 = node @ Wt1^T -> P13 rows 0..399 ; P3 = node @ Wt3^T -> rows 400..799
  gemm_bt<0,1,0><<<dim3(4,6,8), 256, 0, stream>>>(nodeb, wt_b, P13, nullptr,
      HM, HE, HE, HE, 3*HE, HE, (long)HM*HE, 0, (long)840*HE);
  gemm_bt<0,1,0><<<dim3(4,6,8), 256, 0, stream>>>(nodeb, wt_b + 2*HE, P13 + (long)HM*HE, nullptr,
      HM, HE, HE, HE, 3*HE, HE, (long)HM*HE, 0, (long)840*HE);
  bcast_relw2_k<<<(HB*40*HE+255)/256, 256, 0, stream>>>(relW2, P13);
  // scores = hid @ P13^T: batched, M=128, N=840, K=768
  gemm_bt<0,0,0><<<dim3(1,7,8), 256, 0, stream>>>(hid_b, P13, scores, nullptr,
      HL, 840, HE, HE, HE, 840, (long)HL*HE, (long)840*HE, (long)HL*840);

  // logits = hid @ wte^T -> d_out, fused row sum-of-exp
  gemm_bt<0,0,1><<<dim3(8,393,1), 256, 0, stream>>>(hid_b, wte_b, out, rowsum,
      HBL, HV, HE, HE, HE, HV, 0, 0, 0);

  gate_k<<<HBL/4, 256, 0, stream>>>(hs, gw, gb, gatev);
  multihop_k<<<HBL, 256, 0, stream>>>(scores, head, tail, rids, labels, dist, cprob);
  finalize_k<<<HV, 256, 0, stream>>>(out, rowsum, gatev, cprob, vmap, mmask);
}